// Round 2
// baseline (243.091 us; speedup 1.0000x reference)
//
#include <hip/hip_runtime.h>
#include <stdint.h>

// Problem sizes (fixed): B=4, S=2048, D=1024, DQK=128, DV=256
#define SLEN 2048
#define NROWS 8192   // B*S

typedef __attribute__((ext_vector_type(4))) float f32x4;
typedef __attribute__((ext_vector_type(8))) short bf16x8;

__device__ __forceinline__ short f2bf(float f) {
  uint32_t u = __builtin_bit_cast(uint32_t, f);
  u += 0x7FFFu + ((u >> 16) & 1u);
  return (short)(u >> 16);
}
__device__ __forceinline__ float bf2f(short s) {
  uint32_t u = ((uint32_t)(uint16_t)s) << 16;
  return __builtin_bit_cast(float, u);
}
__device__ __forceinline__ f32x4 mfma16(bf16x8 a, bf16x8 b, f32x4 c) {
  return __builtin_amdgcn_mfma_f32_16x16x32_bf16(a, b, c, 0, 0, 0);
}
__device__ __forceinline__ void gld_lds16(const void* g, void* l) {
  __builtin_amdgcn_global_load_lds(
      (const __attribute__((address_space(1))) void*)g,
      (__attribute__((address_space(3))) void*)l, 16, 0, 0);
}

// ---------------------------------------------------------------- prep ------
// blocks [0,4096): X -> Xb (bf16), 8 elems/thread
// blocks [4096,7168): WcatT[768][1024] = concat(Wq,Wk,Wv,Wg)^T, bf16
// blocks [7168,8192): WpT[1024][256] = Wp^T, bf16
// blocks [8192,8195): bcat[768] f32
__global__ __launch_bounds__(256) void k_prep(
    const float* __restrict__ X,
    const float* __restrict__ Wq, const float* __restrict__ bq,
    const float* __restrict__ Wk, const float* __restrict__ bk,
    const float* __restrict__ Wv, const float* __restrict__ bv,
    const float* __restrict__ Wg, const float* __restrict__ bg,
    const float* __restrict__ Wp,
    short* __restrict__ Xb, short* __restrict__ WcatT,
    short* __restrict__ WpT, float* __restrict__ bcat) {
  int blk = blockIdx.x, tid = threadIdx.x;
  if (blk < 4096) {
    size_t e = ((size_t)blk * 256 + tid) * 8;
    f32x4 a = *(const f32x4*)&X[e];
    f32x4 b = *(const f32x4*)&X[e + 4];
    bf16x8 o;
    o[0] = f2bf(a[0]); o[1] = f2bf(a[1]); o[2] = f2bf(a[2]); o[3] = f2bf(a[3]);
    o[4] = f2bf(b[0]); o[5] = f2bf(b[1]); o[6] = f2bf(b[2]); o[7] = f2bf(b[3]);
    *(bf16x8*)&Xb[e] = o;
  } else if (blk < 7168) {
    int flat = (blk - 4096) * 256 + tid;  // < 786432
    int c = flat >> 10, d = flat & 1023;
    float v;
    if (c < 128)      v = Wq[d * 128 + c];
    else if (c < 256) v = Wk[d * 128 + (c - 128)];
    else if (c < 512) v = Wv[d * 256 + (c - 256)];
    else              v = Wg[d * 256 + (c - 512)];
    WcatT[flat] = f2bf(v);
  } else if (blk < 8192) {
    int flat = (blk - 7168) * 256 + tid;  // < 262144
    int n = flat >> 8, k = flat & 255;
    WpT[flat] = f2bf(Wp[(size_t)k * 1024 + n]);
  } else {
    int c = (blk - 8192) * 256 + tid;
    if (c < 768) {
      float v;
      if (c < 128)      v = bq[c];
      else if (c < 256) v = bk[c - 128];
      else if (c < 512) v = bv[c - 256];
      else              v = bg[c - 512];
      bcat[c] = v;
    }
  }
}

// ---------------------------------------------------------------- gemm1 -----
// O[8192][768] = Xb[8192][1024] @ Wcat + bcat   (bf16 in, bf16 out, f32 acc)
__global__ __launch_bounds__(256) void k_gemm1(
    const short* __restrict__ Xb, const short* __restrict__ WcatT,
    const float* __restrict__ bcat, short* __restrict__ O) {
  __shared__ short At[128 * 32];
  __shared__ short Bt[128 * 32];
  const int tid = threadIdx.x;
  const int w = tid >> 6, l = tid & 63, lg = l >> 4, lc = l & 15;
  const int m0 = blockIdx.x * 128, n0 = blockIdx.y * 128;
  const int sr0 = w * 32 + (l >> 2);         // staging rows (16/issue)
  const int scc = (l & 3) * 8;               // staging k offset (elems)
  const int wm = (w >> 1) * 64, wn = (w & 1) * 64;

  f32x4 acc[4][4] = {};
  const short* Ab = Xb + (size_t)m0 * 1024;
  const short* Bb = WcatT + (size_t)n0 * 1024;

  for (int kb = 0; kb < 1024; kb += 32) {
    gld_lds16(Ab + (size_t)sr0 * 1024 + kb + scc, &At[(w * 32) * 32]);
    gld_lds16(Ab + (size_t)(sr0 + 16) * 1024 + kb + scc, &At[(w * 32 + 16) * 32]);
    gld_lds16(Bb + (size_t)sr0 * 1024 + kb + scc, &Bt[(w * 32) * 32]);
    gld_lds16(Bb + (size_t)(sr0 + 16) * 1024 + kb + scc, &Bt[(w * 32 + 16) * 32]);
    __syncthreads();
    bf16x8 af[4], bf[4];
#pragma unroll
    for (int mi = 0; mi < 4; ++mi)
      af[mi] = *(const bf16x8*)&At[(wm + mi * 16 + lc) * 32 + lg * 8];
#pragma unroll
    for (int ni = 0; ni < 4; ++ni)
      bf[ni] = *(const bf16x8*)&Bt[(wn + ni * 16 + lc) * 32 + lg * 8];
#pragma unroll
    for (int mi = 0; mi < 4; ++mi)
#pragma unroll
      for (int ni = 0; ni < 4; ++ni)
        acc[mi][ni] = mfma16(af[mi], bf[ni], acc[mi][ni]);
    __syncthreads();
  }
#pragma unroll
  for (int mi = 0; mi < 4; ++mi) {
    int gr = m0 + wm + mi * 16 + lg * 4;
#pragma unroll
    for (int ni = 0; ni < 4; ++ni) {
      int gc = n0 + wn + ni * 16 + lc;
      float bias = bcat[gc];
#pragma unroll
      for (int r = 0; r < 4; ++r)
        O[(size_t)(gr + r) * 768 + gc] = f2bf(acc[mi][ni][r] + bias);
    }
  }
}

// ---------------------------------------------------------------- mid -------
// blocks [0,4096): q2/k2 row norms; [4096,5120): Vt transpose
__global__ __launch_bounds__(256) void k_mid(
    const short* __restrict__ O, float* __restrict__ q2a,
    float* __restrict__ k2a, short* __restrict__ Vt) {
  __shared__ short tile[64][33];
  int blk = blockIdx.x, tid = threadIdx.x;
  if (blk < 4096) {
    int isK = blk >= 2048;
    int row = (blk & 2047) * 4 + (tid >> 6);
    int l = tid & 63;
    uint32_t u = *(const uint32_t*)&O[(size_t)row * 768 + (isK ? 128 : 0) + l * 2];
    float a = bf2f((short)(u & 0xFFFFu));
    float b = bf2f((short)(u >> 16));
    float s = a * a + b * b;
#pragma unroll
    for (int m = 1; m < 64; m <<= 1) s += __shfl_xor(s, m, 64);
    if (l == 0) (isK ? k2a : q2a)[row] = s;
  } else {
    int t = blk - 4096;
    int b = t >> 8, rem = t & 255;
    int s0 = (rem >> 3) * 64, dv0 = (rem & 7) * 32;
    int r = tid >> 2, cg = (tid & 3) * 8;
    bf16x8 v = *(const bf16x8*)&O[(size_t)(b * SLEN + s0 + r) * 768 + 256 + dv0 + cg];
#pragma unroll
    for (int j = 0; j < 8; ++j) tile[r][cg + j] = v[j];
    __syncthreads();
    int dr = tid >> 3, sg = (tid & 7) * 8;
    bf16x8 ov;
#pragma unroll
    for (int j = 0; j < 8; ++j) ov[j] = tile[sg + j][dr];
    *(bf16x8*)&Vt[(size_t)(b * 256 + dv0 + dr) * SLEN + s0 + sg] = ov;
  }
}

// ---------------------------------------------------------------- attn ------
// Per block: one batch b, 32 q rows. 4 waves. KT=256 per iteration.
// AG[row][dv] = (sum_k w_k V[k][dv] / sum_k w_k) * G[row][dv],  w = 1/max(d2,1e-16)
__global__ __launch_bounds__(256) void k_attn(
    const short* __restrict__ O, const short* __restrict__ Vt,
    const float* __restrict__ q2a, const float* __restrict__ k2a,
    short* __restrict__ AG) {
  __shared__ short Wt[32 * 256];   // XOR-swizzled bf16 weight tile
  __shared__ float dls[4][32];
  const int tid = threadIdx.x;
  const int w = tid >> 6, l = tid & 63, lg = l >> 4, lc = l & 15;
  const int b = blockIdx.x >> 6;
  const int q0 = (blockIdx.x & 63) * 32;
  const int grow0 = b * SLEN + q0;

  bf16x8 qf[2][4];
#pragma unroll
  for (int mi = 0; mi < 2; ++mi)
#pragma unroll
    for (int kf = 0; kf < 4; ++kf)
      qf[mi][kf] = *(const bf16x8*)&O[(size_t)(grow0 + mi * 16 + lc) * 768 + kf * 32 + lg * 8];

  float q2r[2][4];
#pragma unroll
  for (int mi = 0; mi < 2; ++mi)
#pragma unroll
    for (int r = 0; r < 4; ++r)
      q2r[mi][r] = q2a[grow0 + mi * 16 + lg * 4 + r];

  f32x4 acc[2][4] = {};
  float den[2][4] = {};

  for (int kt = 0; kt < SLEN; kt += 256) {
    const int krow = b * SLEN + kt + w * 64;  // this wave's 64-k slice
    f32x4 s[2][4] = {};
#pragma unroll
    for (int nk = 0; nk < 4; ++nk) {
#pragma unroll
      for (int kf = 0; kf < 4; ++kf) {
        bf16x8 kv = *(const bf16x8*)&O[(size_t)(krow + nk * 16 + lc) * 768 + 128 + kf * 32 + lg * 8];
        s[0][nk] = mfma16(qf[0][kf], kv, s[0][nk]);
        s[1][nk] = mfma16(qf[1][kf], kv, s[1][nk]);
      }
    }
    float k2r[4];
#pragma unroll
    for (int nk = 0; nk < 4; ++nk) k2r[nk] = k2a[krow + nk * 16 + lc];
#pragma unroll
    for (int mi = 0; mi < 2; ++mi)
#pragma unroll
      for (int nk = 0; nk < 4; ++nk)
#pragma unroll
        for (int r = 0; r < 4; ++r) {
          float d2 = q2r[mi][r] + k2r[nk] - 2.0f * s[mi][nk][r];
          d2 = fmaxf(d2, 1e-16f);
          float wg = __builtin_amdgcn_rcpf(d2);
          den[mi][r] += wg;
          int rr = mi * 16 + lg * 4 + r;
          int byte = rr * 512 + (w * 64 + nk * 16 + lc) * 2;
          byte ^= (rr & 7) << 4;
          *(short*)((char*)Wt + byte) = f2bf(wg);
        }
    __syncthreads();
    // PV: full 256-k slab, this wave's 64 dv columns
#pragma unroll
    for (int kf2 = 0; kf2 < 8; ++kf2) {
      bf16x8 af0, af1;
      {
        int rr = lc;
        int byte = rr * 512 + kf2 * 64 + lg * 16; byte ^= (rr & 7) << 4;
        af0 = *(const bf16x8*)((const char*)Wt + byte);
      }
      {
        int rr = 16 + lc;
        int byte = rr * 512 + kf2 * 64 + lg * 16; byte ^= (rr & 7) << 4;
        af1 = *(const bf16x8*)((const char*)Wt + byte);
      }
#pragma unroll
      for (int nv = 0; nv < 4; ++nv) {
        bf16x8 bv = *(const bf16x8*)&Vt[(size_t)(b * 256 + w * 64 + nv * 16 + lc) * SLEN + kt + kf2 * 32 + lg * 8];
        acc[0][nv] = mfma16(af0, bv, acc[0][nv]);
        acc[1][nv] = mfma16(af1, bv, acc[1][nv]);
      }
    }
    __syncthreads();
  }
  // denominator: reduce over 16 cols (lc), then across the 4 waves
#pragma unroll
  for (int mi = 0; mi < 2; ++mi)
#pragma unroll
    for (int r = 0; r < 4; ++r) {
      float v = den[mi][r];
      v += __shfl_xor(v, 1, 64); v += __shfl_xor(v, 2, 64);
      v += __shfl_xor(v, 4, 64); v += __shfl_xor(v, 8, 64);
      den[mi][r] = v;
    }
  if (lc == 0) {
#pragma unroll
    for (int mi = 0; mi < 2; ++mi)
#pragma unroll
      for (int r = 0; r < 4; ++r) dls[w][mi * 16 + lg * 4 + r] = den[mi][r];
  }
  __syncthreads();
#pragma unroll
  for (int mi = 0; mi < 2; ++mi)
#pragma unroll
    for (int r = 0; r < 4; ++r) {
      int rr = mi * 16 + lg * 4 + r;
      den[mi][r] = dls[0][rr] + dls[1][rr] + dls[2][rr] + dls[3][rr];
    }
#pragma unroll
  for (int mi = 0; mi < 2; ++mi)
#pragma unroll
    for (int nv = 0; nv < 4; ++nv) {
      int dv = w * 64 + nv * 16 + lc;
#pragma unroll
      for (int r = 0; r < 4; ++r) {
        int row = grow0 + mi * 16 + lg * 4 + r;
        float av = acc[mi][nv][r] / den[mi][r];
        float g = bf2f(O[(size_t)row * 768 + 512 + dv]);
        AG[(size_t)row * 256 + dv] = f2bf(av * g);
      }
    }
}

// ---------------------------------------------------------------- gemm3 -----
// Y[8192][1024] = X + AG[8192][256] @ Wp + bp
__global__ __launch_bounds__(256) void k_gemm3(
    const short* __restrict__ AG, const short* __restrict__ WpT,
    const float* __restrict__ X, const float* __restrict__ bp,
    float* __restrict__ Y) {
  __shared__ short At[128 * 32];
  __shared__ short Bt[128 * 32];
  const int tid = threadIdx.x;
  const int w = tid >> 6, l = tid & 63, lg = l >> 4, lc = l & 15;
  const int m0 = blockIdx.x * 128, n0 = blockIdx.y * 128;
  const int sr0 = w * 32 + (l >> 2);
  const int scc = (l & 3) * 8;
  const int wm = (w >> 1) * 64, wn = (w & 1) * 64;

  f32x4 acc[4][4] = {};
  const short* Ab = AG + (size_t)m0 * 256;
  const short* Bb = WpT + (size_t)n0 * 256;

  for (int kb = 0; kb < 256; kb += 32) {
    gld_lds16(Ab + (size_t)sr0 * 256 + kb + scc, &At[(w * 32) * 32]);
    gld_lds16(Ab + (size_t)(sr0 + 16) * 256 + kb + scc, &At[(w * 32 + 16) * 32]);
    gld_lds16(Bb + (size_t)sr0 * 256 + kb + scc, &Bt[(w * 32) * 32]);
    gld_lds16(Bb + (size_t)(sr0 + 16) * 256 + kb + scc, &Bt[(w * 32 + 16) * 32]);
    __syncthreads();
    bf16x8 af[4], bf[4];
#pragma unroll
    for (int mi = 0; mi < 4; ++mi)
      af[mi] = *(const bf16x8*)&At[(wm + mi * 16 + lc) * 32 + lg * 8];
#pragma unroll
    for (int ni = 0; ni < 4; ++ni)
      bf[ni] = *(const bf16x8*)&Bt[(wn + ni * 16 + lc) * 32 + lg * 8];
#pragma unroll
    for (int mi = 0; mi < 4; ++mi)
#pragma unroll
      for (int ni = 0; ni < 4; ++ni)
        acc[mi][ni] = mfma16(af[mi], bf[ni], acc[mi][ni]);
    __syncthreads();
  }
#pragma unroll
  for (int mi = 0; mi < 4; ++mi) {
    int gr = m0 + wm + mi * 16 + lg * 4;
#pragma unroll
    for (int ni = 0; ni < 4; ++ni) {
      int gc = n0 + wn + ni * 16 + lc;
      float bias = bp[gc];
#pragma unroll
      for (int r = 0; r < 4; ++r) {
        size_t idx = (size_t)(gr + r) * 1024 + gc;
        Y[idx] = acc[mi][ni][r] + X[idx] + bias;
      }
    }
  }
}

// ---------------------------------------------------------------- launch ----
extern "C" void kernel_launch(void* const* d_in, const int* in_sizes, int n_in,
                              void* d_out, int out_size, void* d_ws, size_t ws_size,
                              hipStream_t stream) {
  const float* X  = (const float*)d_in[0];
  const float* Wq = (const float*)d_in[1];
  const float* bq = (const float*)d_in[2];
  const float* Wk = (const float*)d_in[3];
  const float* bk = (const float*)d_in[4];
  const float* Wv = (const float*)d_in[5];
  const float* bv = (const float*)d_in[6];
  const float* Wg = (const float*)d_in[7];
  const float* bg = (const float*)d_in[8];
  const float* Wp = (const float*)d_in[9];
  const float* bp = (const float*)d_in[10];

  char* ws = (char*)d_ws;
  short* Xb    = (short*)(ws + 0);          // 16,777,216 B
  short* WcatT = (short*)(ws + 16777216);   //  1,572,864 B
  short* WpT   = (short*)(ws + 18350080);   //    524,288 B
  float* bcat  = (float*)(ws + 18874368);   //      3,072 B (pad to 4096)
  short* O     = (short*)(ws + 18878464);   // 12,582,912 B  (QKVG bf16)
  short* Vt    = (short*)(ws + 31461376);   //  4,194,304 B
  float* q2a   = (float*)(ws + 35655680);   //     32,768 B
  float* k2a   = (float*)(ws + 35688448);   //     32,768 B
  short* AG    = (short*)(ws + 35721216);   //  4,194,304 B  (total ~39.9 MB)
  float* Y = (float*)d_out;

  hipLaunchKernelGGL(k_prep, dim3(8195), dim3(256), 0, stream,
                     X, Wq, bq, Wk, bk, Wv, bv, Wg, bg, Wp, Xb, WcatT, WpT, bcat);
  hipLaunchKernelGGL(k_gemm1, dim3(64, 6), dim3(256), 0, stream, Xb, WcatT, bcat, O);
  hipLaunchKernelGGL(k_mid, dim3(5120), dim3(256), 0, stream, O, q2a, k2a, Vt);
  hipLaunchKernelGGL(k_attn, dim3(256), dim3(256), 0, stream, O, Vt, q2a, k2a, AG);
  hipLaunchKernelGGL(k_gemm3, dim3(64, 8), dim3(256), 0, stream, AG, WpT, X, bp, Y);
}

// Round 3
// 220.765 us; speedup vs baseline: 1.1011x; 1.1011x over previous
//
#include <hip/hip_runtime.h>
#include <stdint.h>

// Problem sizes (fixed): B=4, S=2048, D=1024, DQK=128, DV=256
#define SLEN 2048
#define NROWS 8192   // B*S

typedef __attribute__((ext_vector_type(4))) float f32x4;
typedef __attribute__((ext_vector_type(8))) short bf16x8;

__device__ __forceinline__ short f2bf(float f) {
  uint32_t u = __builtin_bit_cast(uint32_t, f);
  u += 0x7FFFu + ((u >> 16) & 1u);
  return (short)(u >> 16);
}
__device__ __forceinline__ float bf2f(short s) {
  uint32_t u = ((uint32_t)(uint16_t)s) << 16;
  return __builtin_bit_cast(float, u);
}
__device__ __forceinline__ f32x4 mfma16(bf16x8 a, bf16x8 b, f32x4 c) {
  return __builtin_amdgcn_mfma_f32_16x16x32_bf16(a, b, c, 0, 0, 0);
}
__device__ __forceinline__ void gld_lds16(const void* g, void* l) {
  __builtin_amdgcn_global_load_lds(
      (const __attribute__((address_space(1))) void*)g,
      (__attribute__((address_space(3))) void*)l, 16, 0, 0);
}

// ---------------------------------------------------------------- prep ------
__global__ __launch_bounds__(256) void k_prep(
    const float* __restrict__ X,
    const float* __restrict__ Wq, const float* __restrict__ bq,
    const float* __restrict__ Wk, const float* __restrict__ bk,
    const float* __restrict__ Wv, const float* __restrict__ bv,
    const float* __restrict__ Wg, const float* __restrict__ bg,
    const float* __restrict__ Wp,
    short* __restrict__ Xb, short* __restrict__ WcatT,
    short* __restrict__ WpT, float* __restrict__ bcat) {
  int blk = blockIdx.x, tid = threadIdx.x;
  if (blk < 4096) {
    size_t e = ((size_t)blk * 256 + tid) * 8;
    f32x4 a = *(const f32x4*)&X[e];
    f32x4 b = *(const f32x4*)&X[e + 4];
    bf16x8 o;
    o[0] = f2bf(a[0]); o[1] = f2bf(a[1]); o[2] = f2bf(a[2]); o[3] = f2bf(a[3]);
    o[4] = f2bf(b[0]); o[5] = f2bf(b[1]); o[6] = f2bf(b[2]); o[7] = f2bf(b[3]);
    *(bf16x8*)&Xb[e] = o;
  } else if (blk < 7168) {
    int flat = (blk - 4096) * 256 + tid;  // < 786432
    int c = flat >> 10, d = flat & 1023;
    float v;
    if (c < 128)      v = Wq[d * 128 + c];
    else if (c < 256) v = Wk[d * 128 + (c - 128)];
    else if (c < 512) v = Wv[d * 256 + (c - 256)];
    else              v = Wg[d * 256 + (c - 512)];
    WcatT[flat] = f2bf(v);
  } else if (blk < 8192) {
    int flat = (blk - 7168) * 256 + tid;  // < 262144
    int n = flat >> 8, k = flat & 255;
    WpT[flat] = f2bf(Wp[(size_t)k * 1024 + n]);
  } else {
    int c = (blk - 8192) * 256 + tid;
    if (c < 768) {
      float v;
      if (c < 128)      v = bq[c];
      else if (c < 256) v = bk[c - 128];
      else if (c < 512) v = bv[c - 256];
      else              v = bg[c - 512];
      bcat[c] = v;
    }
  }
}

// ---------------------------------------------------------------- gemm1 -----
// O[8192][768] = Xb[8192][1024] @ Wcat + bcat   (bf16 in, bf16 out, f32 acc)
__global__ __launch_bounds__(256) void k_gemm1(
    const short* __restrict__ Xb, const short* __restrict__ WcatT,
    const float* __restrict__ bcat, short* __restrict__ O) {
  __shared__ short At[128 * 32];
  __shared__ short Bt[128 * 32];
  const int tid = threadIdx.x;
  const int w = tid >> 6, l = tid & 63, lg = l >> 4, lc = l & 15;
  const int m0 = blockIdx.x * 128, n0 = blockIdx.y * 128;
  const int sr0 = w * 32 + (l >> 2);
  const int scc = (l & 3) * 8;
  const int wm = (w >> 1) * 64, wn = (w & 1) * 64;

  f32x4 acc[4][4] = {};
  const short* Ab = Xb + (size_t)m0 * 1024;
  const short* Bb = WcatT + (size_t)n0 * 1024;

  for (int kb = 0; kb < 1024; kb += 32) {
    gld_lds16(Ab + (size_t)sr0 * 1024 + kb + scc, &At[(w * 32) * 32]);
    gld_lds16(Ab + (size_t)(sr0 + 16) * 1024 + kb + scc, &At[(w * 32 + 16) * 32]);
    gld_lds16(Bb + (size_t)sr0 * 1024 + kb + scc, &Bt[(w * 32) * 32]);
    gld_lds16(Bb + (size_t)(sr0 + 16) * 1024 + kb + scc, &Bt[(w * 32 + 16) * 32]);
    __syncthreads();
    bf16x8 af[4], bf[4];
#pragma unroll
    for (int mi = 0; mi < 4; ++mi)
      af[mi] = *(const bf16x8*)&At[(wm + mi * 16 + lc) * 32 + lg * 8];
#pragma unroll
    for (int ni = 0; ni < 4; ++ni)
      bf[ni] = *(const bf16x8*)&Bt[(wn + ni * 16 + lc) * 32 + lg * 8];
#pragma unroll
    for (int mi = 0; mi < 4; ++mi)
#pragma unroll
      for (int ni = 0; ni < 4; ++ni)
        acc[mi][ni] = mfma16(af[mi], bf[ni], acc[mi][ni]);
    __syncthreads();
  }
#pragma unroll
  for (int mi = 0; mi < 4; ++mi) {
    int gr = m0 + wm + mi * 16 + lg * 4;
#pragma unroll
    for (int ni = 0; ni < 4; ++ni) {
      int gc = n0 + wn + ni * 16 + lc;
      float bias = bcat[gc];
#pragma unroll
      for (int r = 0; r < 4; ++r)
        O[(size_t)(gr + r) * 768 + gc] = f2bf(acc[mi][ni][r] + bias);
    }
  }
}

// ---------------------------------------------------------------- mid -------
// blocks [0,4096): q2/k2 row norms; [4096,5120): Vt transpose
__global__ __launch_bounds__(256) void k_mid(
    const short* __restrict__ O, float* __restrict__ q2a,
    float* __restrict__ k2a, short* __restrict__ Vt) {
  __shared__ short tile[64][33];
  int blk = blockIdx.x, tid = threadIdx.x;
  if (blk < 4096) {
    int isK = blk >= 2048;
    int row = (blk & 2047) * 4 + (tid >> 6);
    int l = tid & 63;
    uint32_t u = *(const uint32_t*)&O[(size_t)row * 768 + (isK ? 128 : 0) + l * 2];
    float a = bf2f((short)(u & 0xFFFFu));
    float b = bf2f((short)(u >> 16));
    float s = a * a + b * b;
#pragma unroll
    for (int m = 1; m < 64; m <<= 1) s += __shfl_xor(s, m, 64);
    if (l == 0) (isK ? k2a : q2a)[row] = s;
  } else {
    int t = blk - 4096;
    int b = t >> 8, rem = t & 255;
    int s0 = (rem >> 3) * 64, dv0 = (rem & 7) * 32;
    int r = tid >> 2, cg = (tid & 3) * 8;
    bf16x8 v = *(const bf16x8*)&O[(size_t)(b * SLEN + s0 + r) * 768 + 256 + dv0 + cg];
#pragma unroll
    for (int j = 0; j < 8; ++j) tile[r][cg + j] = v[j];
    __syncthreads();
    int dr = tid >> 3, sg = (tid & 7) * 8;
    bf16x8 ov;
#pragma unroll
    for (int j = 0; j < 8; ++j) ov[j] = tile[sg + j][dr];
    *(bf16x8*)&Vt[(size_t)(b * 256 + dv0 + dr) * SLEN + s0 + sg] = ov;
  }
}

// ---------------------------------------------------------------- attn ------
// Split-K: grid = (b*64+qt)*4 + ks, 1024 blocks. Each block: 32 q rows,
// k's [ks*512, ks*512+512). Writes bf16 numerator partial [32][256] and f32
// denominator partial [32]; k_red combines.
__global__ __launch_bounds__(256) void k_attn(
    const short* __restrict__ O, const short* __restrict__ Vt,
    const float* __restrict__ q2a, const float* __restrict__ k2a,
    short* __restrict__ nump, float* __restrict__ denp) {
  __shared__ short Wt[32 * 256];   // XOR-swizzled bf16 weight tile
  __shared__ float dls[4][32];
  const int tid = threadIdx.x;
  const int w = tid >> 6, l = tid & 63, lg = l >> 4, lc = l & 15;
  const int blk = blockIdx.x;
  const int ks = blk & 3;
  const int qt = (blk >> 2) & 63;
  const int b = blk >> 8;
  const int grow0 = b * SLEN + qt * 32;

  bf16x8 qf[2][4];
#pragma unroll
  for (int mi = 0; mi < 2; ++mi)
#pragma unroll
    for (int kf = 0; kf < 4; ++kf)
      qf[mi][kf] = *(const bf16x8*)&O[(size_t)(grow0 + mi * 16 + lc) * 768 + kf * 32 + lg * 8];

  float q2r[2][4];
#pragma unroll
  for (int mi = 0; mi < 2; ++mi)
#pragma unroll
    for (int r = 0; r < 4; ++r)
      q2r[mi][r] = q2a[grow0 + mi * 16 + lg * 4 + r];

  f32x4 acc[2][4] = {};
  float den[2][4] = {};

  for (int it = 0; it < 2; ++it) {
    const int kt = ks * 512 + it * 256;
    const int krow = b * SLEN + kt + w * 64;  // this wave's 64-k slice
    f32x4 s[2][4] = {};
#pragma unroll
    for (int nk = 0; nk < 4; ++nk) {
#pragma unroll
      for (int kf = 0; kf < 4; ++kf) {
        bf16x8 kv = *(const bf16x8*)&O[(size_t)(krow + nk * 16 + lc) * 768 + 128 + kf * 32 + lg * 8];
        s[0][nk] = mfma16(qf[0][kf], kv, s[0][nk]);
        s[1][nk] = mfma16(qf[1][kf], kv, s[1][nk]);
      }
    }
    float k2r[4];
#pragma unroll
    for (int nk = 0; nk < 4; ++nk) k2r[nk] = k2a[krow + nk * 16 + lc];
#pragma unroll
    for (int mi = 0; mi < 2; ++mi)
#pragma unroll
      for (int nk = 0; nk < 4; ++nk)
#pragma unroll
        for (int r = 0; r < 4; ++r) {
          float d2 = q2r[mi][r] + k2r[nk] - 2.0f * s[mi][nk][r];
          d2 = fmaxf(d2, 1e-16f);
          float wg = __builtin_amdgcn_rcpf(d2);
          den[mi][r] += wg;
          int rr = mi * 16 + lg * 4 + r;
          int byte = rr * 512 + (w * 64 + nk * 16 + lc) * 2;
          byte ^= (rr & 7) << 4;
          *(short*)((char*)Wt + byte) = f2bf(wg);
        }
    __syncthreads();
    // PV: full 256-k slab, this wave's 64 dv columns
#pragma unroll
    for (int kf2 = 0; kf2 < 8; ++kf2) {
      bf16x8 af0, af1;
      {
        int rr = lc;
        int byte = rr * 512 + kf2 * 64 + lg * 16; byte ^= (rr & 7) << 4;
        af0 = *(const bf16x8*)((const char*)Wt + byte);
      }
      {
        int rr = 16 + lc;
        int byte = rr * 512 + kf2 * 64 + lg * 16; byte ^= (rr & 7) << 4;
        af1 = *(const bf16x8*)((const char*)Wt + byte);
      }
#pragma unroll
      for (int nv = 0; nv < 4; ++nv) {
        bf16x8 bv = *(const bf16x8*)&Vt[(size_t)(b * 256 + w * 64 + nv * 16 + lc) * SLEN + kt + kf2 * 32 + lg * 8];
        acc[0][nv] = mfma16(af0, bv, acc[0][nv]);
        acc[1][nv] = mfma16(af1, bv, acc[1][nv]);
      }
    }
    __syncthreads();
  }
  // denominator: reduce over 16 cols (lc), then across the 4 waves
#pragma unroll
  for (int mi = 0; mi < 2; ++mi)
#pragma unroll
    for (int r = 0; r < 4; ++r) {
      float v = den[mi][r];
      v += __shfl_xor(v, 1, 64); v += __shfl_xor(v, 2, 64);
      v += __shfl_xor(v, 4, 64); v += __shfl_xor(v, 8, 64);
      den[mi][r] = v;
    }
  if (lc == 0) {
#pragma unroll
    for (int mi = 0; mi < 2; ++mi)
#pragma unroll
      for (int r = 0; r < 4; ++r) dls[w][mi * 16 + lg * 4 + r] = den[mi][r];
  }
  __syncthreads();
  // partial writes
  const size_t pbase = (size_t)blk * 32 * 256;
#pragma unroll
  for (int mi = 0; mi < 2; ++mi)
#pragma unroll
    for (int nv = 0; nv < 4; ++nv) {
      int dv = w * 64 + nv * 16 + lc;
#pragma unroll
      for (int r = 0; r < 4; ++r) {
        int rit = mi * 16 + lg * 4 + r;
        nump[pbase + (size_t)rit * 256 + dv] = f2bf(acc[mi][nv][r]);
      }
    }
  if (w == 0 && lc == 0) {
#pragma unroll
    for (int mi = 0; mi < 2; ++mi)
#pragma unroll
      for (int r = 0; r < 4; ++r) {
        int rit = mi * 16 + lg * 4 + r;
        denp[blk * 32 + rit] = dls[0][rit] + dls[1][rit] + dls[2][rit] + dls[3][rit];
      }
  }
}

// ---------------------------------------------------------------- red -------
// AG[row][dv] = (sum_ks nump) / (sum_ks denp) * G[row][dv]
__global__ __launch_bounds__(256) void k_red(
    const short* __restrict__ nump, const float* __restrict__ denp,
    const short* __restrict__ O, short* __restrict__ AG) {
  int flat = blockIdx.x * 256 + threadIdx.x;   // 0..262143
  int idx8 = flat * 8;
  int row = idx8 >> 8;
  int dv0 = idx8 & 255;
  int b = row >> 11, srow = row & 2047;
  int qt = srow >> 5, rit = srow & 31;
  int blkbase = (b * 64 + qt) << 2;
  float num[8] = {};
  float den = 0.f;
#pragma unroll
  for (int ksi = 0; ksi < 4; ++ksi) {
    const size_t base = ((size_t)(blkbase + ksi) * 32 + rit) * 256 + dv0;
    bf16x8 v = *(const bf16x8*)&nump[base];
#pragma unroll
    for (int j = 0; j < 8; ++j) num[j] += bf2f(v[j]);
    den += denp[(blkbase + ksi) * 32 + rit];
  }
  float rden = 1.f / den;
  bf16x8 gv = *(const bf16x8*)&O[(size_t)row * 768 + 512 + dv0];
  bf16x8 o;
#pragma unroll
  for (int j = 0; j < 8; ++j) o[j] = f2bf(num[j] * rden * bf2f(gv[j]));
  *(bf16x8*)&AG[idx8] = o;
}

// ---------------------------------------------------------------- gemm3 -----
// Y[8192][1024] = X + AG[8192][256] @ Wp + bp
__global__ __launch_bounds__(256) void k_gemm3(
    const short* __restrict__ AG, const short* __restrict__ WpT,
    const float* __restrict__ X, const float* __restrict__ bp,
    float* __restrict__ Y) {
  __shared__ short At[128 * 32];
  __shared__ short Bt[128 * 32];
  const int tid = threadIdx.x;
  const int w = tid >> 6, l = tid & 63, lg = l >> 4, lc = l & 15;
  const int m0 = blockIdx.x * 128, n0 = blockIdx.y * 128;
  const int sr0 = w * 32 + (l >> 2);
  const int scc = (l & 3) * 8;
  const int wm = (w >> 1) * 64, wn = (w & 1) * 64;

  f32x4 acc[4][4] = {};
  const short* Ab = AG + (size_t)m0 * 256;
  const short* Bb = WpT + (size_t)n0 * 256;

  for (int kb = 0; kb < 256; kb += 32) {
    gld_lds16(Ab + (size_t)sr0 * 256 + kb + scc, &At[(w * 32) * 32]);
    gld_lds16(Ab + (size_t)(sr0 + 16) * 256 + kb + scc, &At[(w * 32 + 16) * 32]);
    gld_lds16(Bb + (size_t)sr0 * 256 + kb + scc, &Bt[(w * 32) * 32]);
    gld_lds16(Bb + (size_t)(sr0 + 16) * 256 + kb + scc, &Bt[(w * 32 + 16) * 32]);
    __syncthreads();
    bf16x8 af[4], bf[4];
#pragma unroll
    for (int mi = 0; mi < 4; ++mi)
      af[mi] = *(const bf16x8*)&At[(wm + mi * 16 + lc) * 32 + lg * 8];
#pragma unroll
    for (int ni = 0; ni < 4; ++ni)
      bf[ni] = *(const bf16x8*)&Bt[(wn + ni * 16 + lc) * 32 + lg * 8];
#pragma unroll
    for (int mi = 0; mi < 4; ++mi)
#pragma unroll
      for (int ni = 0; ni < 4; ++ni)
        acc[mi][ni] = mfma16(af[mi], bf[ni], acc[mi][ni]);
    __syncthreads();
  }
#pragma unroll
  for (int mi = 0; mi < 4; ++mi) {
    int gr = m0 + wm + mi * 16 + lg * 4;
#pragma unroll
    for (int ni = 0; ni < 4; ++ni) {
      int gc = n0 + wn + ni * 16 + lc;
      float bias = bp[gc];
#pragma unroll
      for (int r = 0; r < 4; ++r) {
        size_t idx = (size_t)(gr + r) * 1024 + gc;
        Y[idx] = acc[mi][ni][r] + X[idx] + bias;
      }
    }
  }
}

// ---------------------------------------------------------------- launch ----
extern "C" void kernel_launch(void* const* d_in, const int* in_sizes, int n_in,
                              void* d_out, int out_size, void* d_ws, size_t ws_size,
                              hipStream_t stream) {
  const float* X  = (const float*)d_in[0];
  const float* Wq = (const float*)d_in[1];
  const float* bq = (const float*)d_in[2];
  const float* Wk = (const float*)d_in[3];
  const float* bk = (const float*)d_in[4];
  const float* Wv = (const float*)d_in[5];
  const float* bv = (const float*)d_in[6];
  const float* Wg = (const float*)d_in[7];
  const float* bg = (const float*)d_in[8];
  const float* Wp = (const float*)d_in[9];
  const float* bp = (const float*)d_in[10];

  char* ws = (char*)d_ws;
  short* Xb    = (short*)(ws + 0);          // 16,777,216 B
  short* WcatT = (short*)(ws + 16777216);   //  1,572,864 B
  short* WpT   = (short*)(ws + 18350080);   //    524,288 B
  float* bcat  = (float*)(ws + 18874368);   //      3,072 B (pad to 4096)
  short* O     = (short*)(ws + 18878464);   // 12,582,912 B  (QKVG bf16)
  short* Vt    = (short*)(ws + 31461376);   //  4,194,304 B
  float* q2a   = (float*)(ws + 35655680);   //     32,768 B
  float* k2a   = (float*)(ws + 35688448);   //     32,768 B
  short* AG    = (short*)(ws + 35721216);   //  4,194,304 B  (total ~39.9 MB)
  // Aliases: dead after k_gemm1, reused by split-K attention partials.
  short* nump  = (short*)(ws + 0);          // 16,777,216 B over Xb
  float* denp  = (float*)(ws + 16777216);   //    131,072 B over WcatT
  float* Y = (float*)d_out;

  hipLaunchKernelGGL(k_prep, dim3(8195), dim3(256), 0, stream,
                     X, Wq, bq, Wk, bk, Wv, bv, Wg, bg, Wp, Xb, WcatT, WpT, bcat);
  hipLaunchKernelGGL(k_gemm1, dim3(64, 6), dim3(256), 0, stream, Xb, WcatT, bcat, O);
  hipLaunchKernelGGL(k_mid, dim3(5120), dim3(256), 0, stream, O, q2a, k2a, Vt);
  hipLaunchKernelGGL(k_attn, dim3(1024), dim3(256), 0, stream, O, Vt, q2a, k2a, nump, denp);
  hipLaunchKernelGGL(k_red, dim3(1024), dim3(256), 0, stream, nump, denp, O, AG);
  hipLaunchKernelGGL(k_gemm3, dim3(64, 8), dim3(256), 0, stream, AG, WpT, X, bp, Y);
}

// Round 4
// 214.257 us; speedup vs baseline: 1.1346x; 1.0304x over previous
//
#include <hip/hip_runtime.h>
#include <stdint.h>

// Problem sizes (fixed): B=4, S=2048, D=1024, DQK=128, DV=256
#define SLEN 2048
#define NROWS 8192   // B*S

typedef __attribute__((ext_vector_type(4))) float f32x4;
typedef __attribute__((ext_vector_type(8))) short bf16x8;
typedef __attribute__((ext_vector_type(2))) unsigned int u32x2;

__device__ __forceinline__ short f2bf(float f) {
  uint32_t u = __builtin_bit_cast(uint32_t, f);
  u += 0x7FFFu + ((u >> 16) & 1u);
  return (short)(u >> 16);
}
__device__ __forceinline__ float bf2f(short s) {
  uint32_t u = ((uint32_t)(uint16_t)s) << 16;
  return __builtin_bit_cast(float, u);
}
__device__ __forceinline__ f32x4 mfma16(bf16x8 a, bf16x8 b, f32x4 c) {
  return __builtin_amdgcn_mfma_f32_16x16x32_bf16(a, b, c, 0, 0, 0);
}
__device__ __forceinline__ void gld_lds16(const void* g, void* l) {
  __builtin_amdgcn_global_load_lds(
      (const __attribute__((address_space(1))) void*)g,
      (__attribute__((address_space(3))) void*)l, 16, 0, 0);
}

// ---------------------------------------------------------------- prep ------
// blocks [0,4096): X -> Xb (bf16)
// blocks [4096,4352): 256 LDS-tiled 64x64 weight transposes (coalesced)
// block 4352: bcat
__global__ __launch_bounds__(256) void k_prep(
    const float* __restrict__ X,
    const float* __restrict__ Wq, const float* __restrict__ bq,
    const float* __restrict__ Wk, const float* __restrict__ bk,
    const float* __restrict__ Wv, const float* __restrict__ bv,
    const float* __restrict__ Wg, const float* __restrict__ bg,
    const float* __restrict__ Wp,
    short* __restrict__ Xb, short* __restrict__ WcatT,
    short* __restrict__ WpT, float* __restrict__ bcat) {
  __shared__ short tl[64][72];
  int blk = blockIdx.x, tid = threadIdx.x;
  if (blk < 4096) {
    size_t e = ((size_t)blk * 256 + tid) * 8;
    f32x4 a = *(const f32x4*)&X[e];
    f32x4 b = *(const f32x4*)&X[e + 4];
    bf16x8 o;
    o[0] = f2bf(a[0]); o[1] = f2bf(a[1]); o[2] = f2bf(a[2]); o[3] = f2bf(a[3]);
    o[4] = f2bf(b[0]); o[5] = f2bf(b[1]); o[6] = f2bf(b[2]); o[7] = f2bf(b[3]);
    *(bf16x8*)&Xb[e] = o;
  } else if (blk < 4352) {
    int t = blk - 4096;
    const float* src; short* dst; int C, rowoff, dstC, r0, c0;
    if (t < 32)       { src = Wq; C = 128;  rowoff = 0;   dst = WcatT; dstC = 1024; r0 = (t >> 1) * 64;  c0 = (t & 1) * 64; }
    else if (t < 64)  { t -= 32;  src = Wk; C = 128;  rowoff = 128; dst = WcatT; dstC = 1024; r0 = (t >> 1) * 64;  c0 = (t & 1) * 64; }
    else if (t < 128) { t -= 64;  src = Wv; C = 256;  rowoff = 256; dst = WcatT; dstC = 1024; r0 = (t >> 2) * 64;  c0 = (t & 3) * 64; }
    else if (t < 192) { t -= 128; src = Wg; C = 256;  rowoff = 512; dst = WcatT; dstC = 1024; r0 = (t >> 2) * 64;  c0 = (t & 3) * 64; }
    else              { t -= 192; src = Wp; C = 1024; rowoff = 0;   dst = WpT;   dstC = 256;  r0 = (t >> 4) * 64;  c0 = (t & 15) * 64; }
    int lr = tid >> 4, lcc = tid & 15;
#pragma unroll
    for (int rr = 0; rr < 4; ++rr) {
      f32x4 v = *(const f32x4*)&src[(size_t)(r0 + lr * 4 + rr) * C + c0 + lcc * 4];
#pragma unroll
      for (int j = 0; j < 4; ++j) tl[lcc * 4 + j][lr * 4 + rr] = f2bf(v[j]);
    }
    __syncthreads();
    int orow = tid >> 2, og = (tid & 3) * 16;
    bf16x8 o1, o2;
#pragma unroll
    for (int j = 0; j < 8; ++j) { o1[j] = tl[orow][og + j]; o2[j] = tl[orow][og + 8 + j]; }
    size_t dbase = (size_t)(rowoff + c0 + orow) * dstC + r0 + og;
    *(bf16x8*)&dst[dbase] = o1;
    *(bf16x8*)&dst[dbase + 8] = o2;
  } else {
    int c = tid;
    if (c < 768) {
      float v;
      if (c < 128)      v = bq[c];
      else if (c < 256) v = bk[c - 128];
      else if (c < 512) v = bv[c - 256];
      else              v = bg[c - 512];
      bcat[c] = v;
    }
  }
}

// ---------------------------------------------------------------- gemm1 -----
// O[8192][768] = Xb[8192][1024] @ Wcat + bcat. Blocks with y==0/1 also emit
// q2a/k2a row norms (sum over the 128 Q/K cols of bf16-rounded values).
__global__ __launch_bounds__(256) void k_gemm1(
    const short* __restrict__ Xb, const short* __restrict__ WcatT,
    const float* __restrict__ bcat, short* __restrict__ O,
    float* __restrict__ q2a, float* __restrict__ k2a) {
  __shared__ short At[128 * 32];
  __shared__ short Bt[128 * 32];
  __shared__ float nlds[128][2];
  const int tid = threadIdx.x;
  const int w = tid >> 6, l = tid & 63, lg = l >> 4, lc = l & 15;
  const int m0 = blockIdx.x * 128, n0 = blockIdx.y * 128;
  const int sr0 = w * 32 + (l >> 2);
  const int scc = (l & 3) * 8;
  const int wm = (w >> 1) * 64, wn = (w & 1) * 64;

  f32x4 acc[4][4] = {};
  const short* Ab = Xb + (size_t)m0 * 1024;
  const short* Bb = WcatT + (size_t)n0 * 1024;

  for (int kb = 0; kb < 1024; kb += 32) {
    gld_lds16(Ab + (size_t)sr0 * 1024 + kb + scc, &At[(w * 32) * 32]);
    gld_lds16(Ab + (size_t)(sr0 + 16) * 1024 + kb + scc, &At[(w * 32 + 16) * 32]);
    gld_lds16(Bb + (size_t)sr0 * 1024 + kb + scc, &Bt[(w * 32) * 32]);
    gld_lds16(Bb + (size_t)(sr0 + 16) * 1024 + kb + scc, &Bt[(w * 32 + 16) * 32]);
    __syncthreads();
    bf16x8 af[4], bf[4];
#pragma unroll
    for (int mi = 0; mi < 4; ++mi)
      af[mi] = *(const bf16x8*)&At[(wm + mi * 16 + lc) * 32 + lg * 8];
#pragma unroll
    for (int ni = 0; ni < 4; ++ni)
      bf[ni] = *(const bf16x8*)&Bt[(wn + ni * 16 + lc) * 32 + lg * 8];
#pragma unroll
    for (int mi = 0; mi < 4; ++mi)
#pragma unroll
      for (int ni = 0; ni < 4; ++ni)
        acc[mi][ni] = mfma16(af[mi], bf[ni], acc[mi][ni]);
    __syncthreads();
  }
  float sq[4][4] = {};
#pragma unroll
  for (int mi = 0; mi < 4; ++mi) {
    int gr = m0 + wm + mi * 16 + lg * 4;
#pragma unroll
    for (int ni = 0; ni < 4; ++ni) {
      int gc = n0 + wn + ni * 16 + lc;
      float bias = bcat[gc];
#pragma unroll
      for (int r = 0; r < 4; ++r) {
        short sv = f2bf(acc[mi][ni][r] + bias);
        O[(size_t)(gr + r) * 768 + gc] = sv;
        float v = bf2f(sv);
        sq[mi][r] += v * v;
      }
    }
  }
  if (blockIdx.y < 2) {
    // row-norm: reduce across lc (16 lanes), then across the wave pair
#pragma unroll
    for (int mi = 0; mi < 4; ++mi)
#pragma unroll
      for (int r = 0; r < 4; ++r) {
        float v = sq[mi][r];
        v += __shfl_xor(v, 1, 64); v += __shfl_xor(v, 2, 64);
        v += __shfl_xor(v, 4, 64); v += __shfl_xor(v, 8, 64);
        sq[mi][r] = v;
      }
    if (lc == 0) {
#pragma unroll
      for (int mi = 0; mi < 4; ++mi)
#pragma unroll
        for (int r = 0; r < 4; ++r)
          nlds[wm + mi * 16 + lg * 4 + r][w & 1] = sq[mi][r];
    }
    __syncthreads();
    if (tid < 128) {
      float t = nlds[tid][0] + nlds[tid][1];
      (blockIdx.y == 0 ? q2a : k2a)[m0 + tid] = t;
    }
  }
}

// ---------------------------------------------------------------- vt --------
// Vt[b*256+dv][s] = V row-major -> transposed (for PV B-operand)
__global__ __launch_bounds__(256) void k_vt(
    const short* __restrict__ O, short* __restrict__ Vt) {
  __shared__ short tile[64][33];
  int blk = blockIdx.x, tid = threadIdx.x;
  int b = blk >> 8, rem = blk & 255;
  int s0 = (rem >> 3) * 64, dv0 = (rem & 7) * 32;
  int r = tid >> 2, cg = (tid & 3) * 8;
  bf16x8 v = *(const bf16x8*)&O[(size_t)(b * SLEN + s0 + r) * 768 + 256 + dv0 + cg];
#pragma unroll
  for (int j = 0; j < 8; ++j) tile[r][cg + j] = v[j];
  __syncthreads();
  int dr = tid >> 3, sg = (tid & 7) * 8;
  bf16x8 ov;
#pragma unroll
  for (int j = 0; j < 8; ++j) ov[j] = tile[sg + j][dr];
  *(bf16x8*)&Vt[(size_t)(b * 256 + dv0 + dr) * SLEN + s0 + sg] = ov;
}

// ---------------------------------------------------------------- attn ------
// Split-K, swapped-QK formulation: s = mfma(K,Q) puts k lane-local so the
// 1/d2 transform packs 4 bf16 -> one ds_write_b64. XCD-swizzled blockIdx.
__global__ __launch_bounds__(256) void k_attn(
    const short* __restrict__ O, const short* __restrict__ Vt,
    const float* __restrict__ q2a, const float* __restrict__ k2a,
    short* __restrict__ nump, float* __restrict__ denp) {
  __shared__ short Wt[32 * 256];   // [32 q][256 k], XOR-swizzled rows
  __shared__ float dls[4][32];
  const int tid = threadIdx.x;
  const int w = tid >> 6, l = tid & 63, lg = l >> 4, lc = l & 15;
  const int blk = ((blockIdx.x & 7) << 7) | (blockIdx.x >> 3);  // XCD swizzle (1024%8==0)
  const int ks = blk & 3;
  const int qt = (blk >> 2) & 63;
  const int b = blk >> 8;
  const int grow0 = b * SLEN + qt * 32;

  bf16x8 qf[2][4];
#pragma unroll
  for (int mi = 0; mi < 2; ++mi)
#pragma unroll
    for (int kf = 0; kf < 4; ++kf)
      qf[mi][kf] = *(const bf16x8*)&O[(size_t)(grow0 + mi * 16 + lc) * 768 + kf * 32 + lg * 8];

  float q2s[2];
  q2s[0] = q2a[grow0 + lc];
  q2s[1] = q2a[grow0 + 16 + lc];

  f32x4 acc[2][4] = {};
  float den0 = 0.f, den1 = 0.f;

  for (int it = 0; it < 2; ++it) {
    const int kt = ks * 512 + it * 256;
    const int krow = b * SLEN + kt + w * 64;  // this wave's 64-k slice
    f32x4 s[2][4] = {};
#pragma unroll
    for (int nk = 0; nk < 4; ++nk) {
#pragma unroll
      for (int kf = 0; kf < 4; ++kf) {
        bf16x8 kv = *(const bf16x8*)&O[(size_t)(krow + nk * 16 + lc) * 768 + 128 + kf * 32 + lg * 8];
        s[0][nk] = mfma16(kv, qf[0][kf], s[0][nk]);   // swapped: D[k][q]
        s[1][nk] = mfma16(kv, qf[1][kf], s[1][nk]);
      }
    }
    // transform: lane holds k = nk*16+lg*4+r (contiguous quad), q = mi*16+lc
#pragma unroll
    for (int nk = 0; nk < 4; ++nk) {
      f32x4 k2v = *(const f32x4*)&k2a[krow + nk * 16 + lg * 4];
      float wv[2][4];
#pragma unroll
      for (int mi = 0; mi < 2; ++mi)
#pragma unroll
        for (int r = 0; r < 4; ++r) {
          float d2 = q2s[mi] + k2v[r] - 2.0f * s[mi][nk][r];
          d2 = fmaxf(d2, 1e-16f);
          wv[mi][r] = __builtin_amdgcn_rcpf(d2);
        }
      den0 += wv[0][0] + wv[0][1] + wv[0][2] + wv[0][3];
      den1 += wv[1][0] + wv[1][1] + wv[1][2] + wv[1][3];
      int col = w * 64 + nk * 16 + lg * 4;
#pragma unroll
      for (int mi = 0; mi < 2; ++mi) {
        u32x2 pk;
        pk[0] = (uint32_t)(uint16_t)f2bf(wv[mi][0]) | ((uint32_t)(uint16_t)f2bf(wv[mi][1]) << 16);
        pk[1] = (uint32_t)(uint16_t)f2bf(wv[mi][2]) | ((uint32_t)(uint16_t)f2bf(wv[mi][3]) << 16);
        int q = mi * 16 + lc;
        int byte = q * 512 + col * 2;
        byte ^= (q & 7) << 4;
        *(u32x2*)((char*)Wt + byte) = pk;
      }
    }
    __syncthreads();
    // PV: full 256-k slab, this wave's 64 dv columns
#pragma unroll
    for (int kf2 = 0; kf2 < 8; ++kf2) {
      bf16x8 af0, af1;
      {
        int rr = lc;
        int byte = rr * 512 + kf2 * 64 + lg * 16; byte ^= (rr & 7) << 4;
        af0 = *(const bf16x8*)((const char*)Wt + byte);
      }
      {
        int rr = 16 + lc;
        int byte = rr * 512 + kf2 * 64 + lg * 16; byte ^= (rr & 7) << 4;
        af1 = *(const bf16x8*)((const char*)Wt + byte);
      }
#pragma unroll
      for (int nv = 0; nv < 4; ++nv) {
        bf16x8 bv = *(const bf16x8*)&Vt[(size_t)(b * 256 + w * 64 + nv * 16 + lc) * SLEN + kt + kf2 * 32 + lg * 8];
        acc[0][nv] = mfma16(af0, bv, acc[0][nv]);
        acc[1][nv] = mfma16(af1, bv, acc[1][nv]);
      }
    }
    __syncthreads();
  }
  // den: sum across lg groups (k-slices within wave), publish per-wave
  den0 += __shfl_xor(den0, 16, 64); den0 += __shfl_xor(den0, 32, 64);
  den1 += __shfl_xor(den1, 16, 64); den1 += __shfl_xor(den1, 32, 64);
  if (l < 16) { dls[w][lc] = den0; dls[w][16 + lc] = den1; }
  __syncthreads();
  // partial writes
  const size_t pbase = (size_t)blk * 32 * 256;
#pragma unroll
  for (int mi = 0; mi < 2; ++mi)
#pragma unroll
    for (int nv = 0; nv < 4; ++nv) {
      int dv = w * 64 + nv * 16 + lc;
#pragma unroll
      for (int r = 0; r < 4; ++r) {
        int rit = mi * 16 + lg * 4 + r;
        nump[pbase + (size_t)rit * 256 + dv] = f2bf(acc[mi][nv][r]);
      }
    }
  if (tid < 32)
    denp[blk * 32 + tid] = dls[0][tid] + dls[1][tid] + dls[2][tid] + dls[3][tid];
}

// ---------------------------------------------------------------- red -------
// AG[row][dv] = (sum_ks nump) / (sum_ks denp) * G[row][dv]
__global__ __launch_bounds__(256) void k_red(
    const short* __restrict__ nump, const float* __restrict__ denp,
    const short* __restrict__ O, short* __restrict__ AG) {
  int flat = blockIdx.x * 256 + threadIdx.x;   // 0..262143
  int idx8 = flat * 8;
  int row = idx8 >> 8;
  int dv0 = idx8 & 255;
  int b = row >> 11, srow = row & 2047;
  int qt = srow >> 5, rit = srow & 31;
  int blkbase = (b * 64 + qt) << 2;
  float num[8] = {};
  float den = 0.f;
#pragma unroll
  for (int ksi = 0; ksi < 4; ++ksi) {
    const size_t base = ((size_t)(blkbase + ksi) * 32 + rit) * 256 + dv0;
    bf16x8 v = *(const bf16x8*)&nump[base];
#pragma unroll
    for (int j = 0; j < 8; ++j) num[j] += bf2f(v[j]);
    den += denp[(blkbase + ksi) * 32 + rit];
  }
  float rden = 1.f / den;
  bf16x8 gv = *(const bf16x8*)&O[(size_t)row * 768 + 512 + dv0];
  bf16x8 o;
#pragma unroll
  for (int j = 0; j < 8; ++j) o[j] = f2bf(num[j] * rden * bf2f(gv[j]));
  *(bf16x8*)&AG[idx8] = o;
}

// ---------------------------------------------------------------- gemm3 -----
// Y[8192][1024] = X + AG[8192][256] @ Wp + bp
__global__ __launch_bounds__(256) void k_gemm3(
    const short* __restrict__ AG, const short* __restrict__ WpT,
    const float* __restrict__ X, const float* __restrict__ bp,
    float* __restrict__ Y) {
  __shared__ short At[128 * 32];
  __shared__ short Bt[128 * 32];
  const int tid = threadIdx.x;
  const int w = tid >> 6, l = tid & 63, lg = l >> 4, lc = l & 15;
  const int m0 = blockIdx.x * 128, n0 = blockIdx.y * 128;
  const int sr0 = w * 32 + (l >> 2);
  const int scc = (l & 3) * 8;
  const int wm = (w >> 1) * 64, wn = (w & 1) * 64;

  f32x4 acc[4][4] = {};
  const short* Ab = AG + (size_t)m0 * 256;
  const short* Bb = WpT + (size_t)n0 * 256;

  for (int kb = 0; kb < 256; kb += 32) {
    gld_lds16(Ab + (size_t)sr0 * 256 + kb + scc, &At[(w * 32) * 32]);
    gld_lds16(Ab + (size_t)(sr0 + 16) * 256 + kb + scc, &At[(w * 32 + 16) * 32]);
    gld_lds16(Bb + (size_t)sr0 * 256 + kb + scc, &Bt[(w * 32) * 32]);
    gld_lds16(Bb + (size_t)(sr0 + 16) * 256 + kb + scc, &Bt[(w * 32 + 16) * 32]);
    __syncthreads();
    bf16x8 af[4], bf[4];
#pragma unroll
    for (int mi = 0; mi < 4; ++mi)
      af[mi] = *(const bf16x8*)&At[(wm + mi * 16 + lc) * 32 + lg * 8];
#pragma unroll
    for (int ni = 0; ni < 4; ++ni)
      bf[ni] = *(const bf16x8*)&Bt[(wn + ni * 16 + lc) * 32 + lg * 8];
#pragma unroll
    for (int mi = 0; mi < 4; ++mi)
#pragma unroll
      for (int ni = 0; ni < 4; ++ni)
        acc[mi][ni] = mfma16(af[mi], bf[ni], acc[mi][ni]);
    __syncthreads();
  }
#pragma unroll
  for (int mi = 0; mi < 4; ++mi) {
    int gr = m0 + wm + mi * 16 + lg * 4;
#pragma unroll
    for (int ni = 0; ni < 4; ++ni) {
      int gc = n0 + wn + ni * 16 + lc;
      float bias = bp[gc];
#pragma unroll
      for (int r = 0; r < 4; ++r) {
        size_t idx = (size_t)(gr + r) * 1024 + gc;
        Y[idx] = acc[mi][ni][r] + X[idx] + bias;
      }
    }
  }
}

// ---------------------------------------------------------------- launch ----
extern "C" void kernel_launch(void* const* d_in, const int* in_sizes, int n_in,
                              void* d_out, int out_size, void* d_ws, size_t ws_size,
                              hipStream_t stream) {
  const float* X  = (const float*)d_in[0];
  const float* Wq = (const float*)d_in[1];
  const float* bq = (const float*)d_in[2];
  const float* Wk = (const float*)d_in[3];
  const float* bk = (const float*)d_in[4];
  const float* Wv = (const float*)d_in[5];
  const float* bv = (const float*)d_in[6];
  const float* Wg = (const float*)d_in[7];
  const float* bg = (const float*)d_in[8];
  const float* Wp = (const float*)d_in[9];
  const float* bp = (const float*)d_in[10];

  char* ws = (char*)d_ws;
  short* Xb    = (short*)(ws + 0);          // 16,777,216 B
  short* WcatT = (short*)(ws + 16777216);   //  1,572,864 B
  short* WpT   = (short*)(ws + 18350080);   //    524,288 B
  float* bcat  = (float*)(ws + 18874368);   //      3,072 B (pad to 4096)
  short* O     = (short*)(ws + 18878464);   // 12,582,912 B  (QKVG bf16)
  short* Vt    = (short*)(ws + 31461376);   //  4,194,304 B
  float* q2a   = (float*)(ws + 35655680);   //     32,768 B
  float* k2a   = (float*)(ws + 35688448);   //     32,768 B
  short* AG    = (short*)(ws + 35721216);   //  4,194,304 B  (total ~39.9 MB)
  // Aliases: dead after k_gemm1, reused by split-K attention partials.
  short* nump  = (short*)(ws + 0);          // 16,777,216 B over Xb
  float* denp  = (float*)(ws + 16777216);   //    131,072 B over WcatT
  float* Y = (float*)d_out;

  hipLaunchKernelGGL(k_prep, dim3(4353), dim3(256), 0, stream,
                     X, Wq, bq, Wk, bk, Wv, bv, Wg, bg, Wp, Xb, WcatT, WpT, bcat);
  hipLaunchKernelGGL(k_gemm1, dim3(64, 6), dim3(256), 0, stream, Xb, WcatT, bcat, O, q2a, k2a);
  hipLaunchKernelGGL(k_vt, dim3(1024), dim3(256), 0, stream, O, Vt);
  hipLaunchKernelGGL(k_attn, dim3(1024), dim3(256), 0, stream, O, Vt, q2a, k2a, nump, denp);
  hipLaunchKernelGGL(k_red, dim3(1024), dim3(256), 0, stream, nump, denp, O, AG);
  hipLaunchKernelGGL(k_gemm3, dim3(64, 8), dim3(256), 0, stream, AG, WpT, X, bp, Y);
}